// Round 6
// baseline (456.164 us; speedup 1.0000x reference)
//
#include <hip/hip_runtime.h>
#include <hip/hip_bf16.h>

#define NN 10000
#define FDIN 1024
#define HH 256
#define CAP 64
#define MPAD 10112        // 316 * 32
#define WT_BLOCKS 1536    // (FDIN*HH + 2*HH*HH) / 256

typedef unsigned short u16;
typedef unsigned int u32;
typedef __attribute__((ext_vector_type(8))) short short8;
typedef __attribute__((ext_vector_type(4))) float f32x4;

__device__ __forceinline__ float ld_in(const void* p, size_t i, int bf) {
    if (bf) {
        unsigned short u = ((const unsigned short*)p)[i];
        return __uint_as_float(((unsigned int)u) << 16);
    }
    return ((const float*)p)[i];
}

__device__ __forceinline__ u16 bf16bits(float x) {
    __hip_bfloat16 h = __float2bfloat16(x);   // RNE
    return *(u16*)&h;
}

__device__ __forceinline__ float bf16val(u16 u) {
    return __uint_as_float(((unsigned int)u) << 16);
}

// Per-block dtype detect (512 B broadcast read, L2-hit after first block).
__device__ __forceinline__ int local_flag(const void* feat, int tid, int* cnts) {
    u16 u = ((const u16*)feat)[2 * tid];
    int e = (u >> 7) & 0xFF;
    bool pred = (e >= 100 && e <= 137);
    unsigned long long b = __ballot(pred);
    if ((tid & 63) == 0) cnts[tid >> 6] = __popcll(b);
    __syncthreads();
    return (cnts[0] + cnts[1] + cnts[2] + cnts[3]) >= 128;
}

// Launch 1 (low-LDS): blocks [0,NN) adjacency scan -> ELL + dinv;
// blocks [NN, NN+WT_BLOCKS) weight transpose -> bf16 K-major. Publishes flag.
__global__ __launch_bounds__(256) void k_scanwt(const void* __restrict__ feat,
                                                const void* __restrict__ adj,
                                                const void* __restrict__ W0,
                                                const void* __restrict__ W1,
                                                const void* __restrict__ W2,
                                                int* __restrict__ flag,
                                                int* __restrict__ ellc,
                                                float* __restrict__ ellv,
                                                int* __restrict__ cnt,
                                                float* __restrict__ dinv,
                                                u16* __restrict__ w0t,
                                                u16* __restrict__ w1t,
                                                u16* __restrict__ w2t) {
    __shared__ int cnts[4];
    __shared__ int s_cnt;
    __shared__ float s_sum;
    int tid = threadIdx.x;
    int bid = blockIdx.x;
    if (tid == 0) { s_cnt = 0; s_sum = 0.f; }
    int f = local_flag(feat, tid, cnts);   // includes one __syncthreads
    if (bid == 0 && tid == 0) *flag = f;

    if (bid < NN) {
        int i = bid;
        float lsum = 0.f;
        if (f) {
            const uint4* p = (const uint4*)((const u16*)adj + (size_t)i * NN);
            for (int t = tid; t < NN / 8; t += 256) {
                uint4 q = p[t];
                if ((q.x | q.y | q.z | q.w) == 0u) continue;   // ~98% of groups
                unsigned int w_[4] = {q.x, q.y, q.z, q.w};
                #pragma unroll
                for (int w = 0; w < 4; ++w) {
                    #pragma unroll
                    for (int hh = 0; hh < 2; ++hh) {
                        unsigned short u = (unsigned short)(w_[w] >> (16 * hh));
                        if (u) {
                            float v = bf16val(u);
                            lsum += v;
                            int slot = atomicAdd(&s_cnt, 1);
                            if (slot < CAP) {
                                ellc[(size_t)i * CAP + slot] = t * 8 + w * 2 + hh;
                                ellv[(size_t)i * CAP + slot] = v;
                            }
                        }
                    }
                }
            }
        } else {
            const uint4* p = (const uint4*)((const float*)adj + (size_t)i * NN);
            for (int t = tid; t < NN / 4; t += 256) {
                uint4 qi = p[t];
                if ((qi.x | qi.y | qi.z | qi.w) == 0u) continue;
                unsigned int w_[4] = {qi.x, qi.y, qi.z, qi.w};
                #pragma unroll
                for (int w = 0; w < 4; ++w) {
                    float v = __uint_as_float(w_[w]);
                    if (v != 0.f) {
                        lsum += v;
                        int slot = atomicAdd(&s_cnt, 1);
                        if (slot < CAP) {
                            ellc[(size_t)i * CAP + slot] = t * 4 + w;
                            ellv[(size_t)i * CAP + slot] = v;
                        }
                    }
                }
            }
        }
        for (int off = 32; off > 0; off >>= 1) lsum += __shfl_down(lsum, off, 64);
        if ((tid & 63) == 0) atomicAdd(&s_sum, lsum);
        __syncthreads();
        if (tid == 0) {
            float deg = s_sum + 1.0f;
            dinv[i] = rsqrtf(deg);
            cnt[i] = s_cnt < CAP ? s_cnt : CAP;
        }
        return;
    }
    int idx = (bid - NN) * 256 + tid;
    const void* W; u16* Wt; int K;
    if (idx < FDIN * HH)                { W = W0; Wt = w0t; K = FDIN; }
    else if (idx < FDIN * HH + HH * HH) { W = W1; Wt = w1t; K = HH; idx -= FDIN * HH; }
    else                                { W = W2; Wt = w2t; K = HH; idx -= FDIN * HH + HH * HH; }
    int k = idx >> 8, n = idx & 255;
    Wt[(size_t)n * K + k] = bf16bits(ld_in(W, (size_t)idx, f));
}

// ---- MFMA GEMM: BM=32, BN=128, BK=64; 632 blocks (~2.5/CU for stall overlap).
// 4 waves as 2m x 2n; wave tile 16x64 (acc[4] of 16x16 frags).
// XOR-16B LDS swizzle on both write and read (rule #21 involution).

// A-fragment load: 16 bf16 elems; inline-converts fp32 when f==0.
__device__ __forceinline__ uint4 load_a(const void* A, int f, size_t row, int K, int e0) {
    if (f) return *(const uint4*)((const u16*)A + row * K + e0);
    const float* fp = (const float*)A + row * K + e0;
    float4 v0 = *(const float4*)fp, v1 = *(const float4*)(fp + 4);
    float4 v2 = *(const float4*)(fp + 8), v3 = *(const float4*)(fp + 12);
    float vv[16] = {v0.x, v0.y, v0.z, v0.w, v1.x, v1.y, v1.z, v1.w,
                    v2.x, v2.y, v2.z, v2.w, v3.x, v3.y, v3.z, v3.w};
    u16 o[16];
    #pragma unroll
    for (int e = 0; e < 16; ++e) o[e] = bf16bits(vv[e]);
    return *(const uint4*)o;
}

__device__ __forceinline__ void lds_store(unsigned char* Asb, unsigned char* Bsb, int tid,
                                          uint4 sa, const uint4* sb) {
    {
        int row = tid >> 3, b = (tid & 7) << 4;
        *(uint4*)(Asb + row * 128 + (b ^ ((row & 7) << 4))) = sa;
    }
    #pragma unroll
    for (int q = 0; q < 4; ++q) {
        int c = q * 256 + tid, n = c >> 3, b = (c & 7) << 4;
        *(uint4*)(Bsb + n * 128 + (b ^ ((n & 7) << 4))) = sb[q];
    }
}

__device__ __forceinline__ void compute64(const unsigned char* Asb, const unsigned char* Bsb,
                                          int l, int wm, int wn, f32x4 acc[4]) {
    #pragma unroll
    for (int kk = 0; kk < 2; ++kk) {
        int kb = kk * 64 + ((l >> 4) << 4);
        int row = wm * 16 + (l & 15);
        short8 av = *(const short8*)(Asb + row * 128 + (kb ^ ((row & 7) << 4)));
        #pragma unroll
        for (int j = 0; j < 4; ++j) {
            int n = wn * 64 + j * 16 + (l & 15);
            short8 bv = *(const short8*)(Bsb + n * 128 + (kb ^ ((n & 7) << 4)));
            acc[j] = __builtin_amdgcn_mfma_f32_16x16x32_bf16(av, bv, acc[j], 0, 0, 0);
        }
    }
}

__device__ __forceinline__ void gemm_body(const void* A, int f, const u16* Bt,
                                          u16* Y, int K, int m0, int n0, int tid,
                                          unsigned char* Asb, unsigned char* Bsb) {
    const int l = tid & 63;
    const int wid = tid >> 6;
    const int wm = wid >> 1, wn = wid & 1;
    f32x4 acc[4] = {};
    uint4 sa, sb[4], ta, tb[4];
    auto g_load = [&](int k0, uint4& xa, uint4* xb) {
        {
            int row = tid >> 3, e0 = (tid & 7) << 3;
            uint4 v = {0u, 0u, 0u, 0u};
            if (m0 + row < NN) v = load_a(A, f, (size_t)(m0 + row), K, k0 + e0);
            xa = v;
        }
        #pragma unroll
        for (int q = 0; q < 4; ++q) {
            int c = q * 256 + tid, n = c >> 3, b = (c & 7) << 4;
            xb[q] = *(const uint4*)((const unsigned char*)(Bt + (size_t)(n0 + n) * K + k0) + b);
        }
    };
    g_load(0, sa, sb);
    const int nt = K >> 6;
    for (int t = 0; t < nt; t += 2) {
        __syncthreads();
        lds_store(Asb, Bsb, tid, sa, sb);
        __syncthreads();
        g_load((t + 1) << 6, ta, tb);
        compute64(Asb, Bsb, l, wm, wn, acc);
        __syncthreads();
        lds_store(Asb, Bsb, tid, ta, tb);
        __syncthreads();
        if (t + 2 < nt) g_load((t + 2) << 6, sa, sb);
        compute64(Asb, Bsb, l, wm, wn, acc);
    }
    int r0 = m0 + wm * 16 + ((l >> 4) << 2);
    #pragma unroll
    for (int j = 0; j < 4; ++j) {
        int col = n0 + wn * 64 + j * 16 + (l & 15);
        #pragma unroll
        for (int r = 0; r < 4; ++r)
            Y[(size_t)(r0 + r) * HH + col] = bf16bits(acc[j][r]);
    }
}

// f_mode: 1 = read *flag (layer 1, A may be fp32), 0 = A is bf16 (layers 2/3).
__global__ __launch_bounds__(256) void k_mfma(const void* __restrict__ A,
                                              const u16* __restrict__ Bt,
                                              const int* __restrict__ flag,
                                              int f_mode,
                                              u16* __restrict__ Y, int K) {
    __shared__ uint4 As4[256];    // 4 KB : 32 rows x 128 B
    __shared__ uint4 Bs4[1024];   // 16 KB: 128 rows x 128 B
    int tid = threadIdx.x;
    int f = f_mode ? *flag : 1;
    int m0 = blockIdx.y * 32;
    int n0 = blockIdx.x * 128;
    gemm_body(A, f, Bt, Y, K, m0, n0, tid,
              (unsigned char*)As4, (unsigned char*)Bs4);
}

// 2 nodes per block: threads [0,128) -> node 2*bid, [128,256) -> node 2*bid+1.
// x_out[i,:] = bf16(relu(dinv_i*(sum_e w*dinv_c*y[c,:] + dinv_i*y[i,:]) + bias))
__global__ __launch_bounds__(256) void k_agg(const u32* __restrict__ y,
                                             const int* __restrict__ ellc,
                                             const float* __restrict__ ellv,
                                             const int* __restrict__ cnt,
                                             const float* __restrict__ dinv,
                                             const void* __restrict__ bias,
                                             const int* __restrict__ flag,
                                             u32* __restrict__ xout) {
    int i = blockIdx.x * 2 + (threadIdx.x >> 7);
    int j = threadIdx.x & 127;
    int f = *flag;
    float di = dinv[i];
    u32 w = y[(size_t)i * 128 + j];
    float a0 = di * bf16val((u16)(w & 0xffff));
    float a1 = di * bf16val((u16)(w >> 16));
    int c_ = cnt[i];
    for (int e = 0; e < c_; ++e) {
        int c = ellc[(size_t)i * CAP + e];
        float s = ellv[(size_t)i * CAP + e] * dinv[c];
        u32 v = y[(size_t)c * 128 + j];
        a0 = fmaf(s, bf16val((u16)(v & 0xffff)), a0);
        a1 = fmaf(s, bf16val((u16)(v >> 16)), a1);
    }
    float v0 = fmaf(di, a0, ld_in(bias, (size_t)(2 * j), f));
    float v1 = fmaf(di, a1, ld_in(bias, (size_t)(2 * j + 1), f));
    v0 = v0 > 0.f ? v0 : 0.f;
    v1 = v1 > 0.f ? v1 : 0.f;
    xout[(size_t)i * 128 + j] = (u32)bf16bits(v0) | ((u32)bf16bits(v1) << 16);
}

// 40 blocks x 250 rows; per-block partial max/sum, no atomics.
__global__ __launch_bounds__(256) void k_pool(const u16* __restrict__ x,
                                              float* __restrict__ pmax,
                                              float* __restrict__ psum) {
    int j = threadIdx.x, b = blockIdx.x;
    int r0 = b * 250;
    float m = 0.f, s = 0.f;
    for (int r = r0; r < r0 + 250; ++r) {
        float v = bf16val(x[(size_t)r * HH + j]);
        m = fmaxf(m, v);
        s += v;
    }
    pmax[b * HH + j] = m;
    psum[b * HH + j] = s;
}

__global__ __launch_bounds__(256) void k_head(const float* __restrict__ pmax,
                                              const float* __restrict__ psum,
                                              const void* C1w, const void* c1b,
                                              const void* C2w, const void* c2b,
                                              const void* C3w, const void* c3b,
                                              const int* __restrict__ flag,
                                              void* __restrict__ out) {
    __shared__ float gs[2 * HH], h1[HH], h2[HH / 2];
    int j = threadIdx.x;
    int f = *flag;
    float m = 0.f, s = 0.f;
    #pragma unroll 4
    for (int b = 0; b < 40; ++b) {
        m = fmaxf(m, pmax[b * HH + j]);
        s += psum[b * HH + j];
    }
    gs[j] = m;
    gs[HH + j] = s * (1.0f / (float)NN);
    __syncthreads();
    float a = 0.f;
    for (int k = 0; k < 2 * HH; ++k) a = fmaf(gs[k], ld_in(C1w, (size_t)k * HH + j, f), a);
    a += ld_in(c1b, j, f);
    h1[j] = a > 0.f ? a : 0.f;
    __syncthreads();
    if (j < HH / 2) {
        float b2_ = 0.f;
        for (int k = 0; k < HH; ++k) b2_ = fmaf(h1[k], ld_in(C2w, (size_t)k * (HH / 2) + j, f), b2_);
        b2_ += ld_in(c2b, j, f);
        h2[j] = b2_ > 0.f ? b2_ : 0.f;
    }
    __syncthreads();
    if (j < 3) {
        float o = 0.f;
        for (int k = 0; k < HH / 2; ++k) o = fmaf(h2[k], ld_in(C3w, (size_t)k * 3 + j, f), o);
        o += ld_in(c3b, j, f);
        if (f) ((__hip_bfloat16*)out)[j] = __float2bfloat16(o);
        else   ((float*)out)[j] = o;
    }
}

extern "C" void kernel_launch(void* const* d_in, const int* in_sizes, int n_in,
                              void* d_out, int out_size, void* d_ws, size_t ws_size,
                              hipStream_t stream) {
    const void* feat = d_in[0];
    const void* adj  = d_in[1];
    const void* W0 = d_in[2];  const void* b0 = d_in[3];
    const void* W1 = d_in[4];  const void* b1 = d_in[5];
    const void* W2 = d_in[6];  const void* b2 = d_in[7];
    const void* C1w = d_in[8]; const void* c1b = d_in[9];
    const void* C2w = d_in[10]; const void* c2b = d_in[11];
    const void* C3w = d_in[12]; const void* c3b = d_in[13];

    char* ws = (char*)d_ws;
    size_t o = 0;
    auto take = [&](size_t bytes) -> void* {
        void* p = ws + o;
        o += (bytes + 255) & ~(size_t)255;
        return p;
    };
    int*   flag  = (int*)take(4);
    float* dinv  = (float*)take((size_t)NN * 4);
    int*   cnt   = (int*)take((size_t)NN * 4);
    int*   ellc  = (int*)take((size_t)NN * CAP * 4);
    float* ellv  = (float*)take((size_t)NN * CAP * 4);
    u16*   w0t   = (u16*)take((size_t)HH * FDIN * 2);
    u16*   w1t   = (u16*)take((size_t)HH * HH * 2);
    u16*   w2t   = (u16*)take((size_t)HH * HH * 2);
    u16*   xbuf  = (u16*)take((size_t)MPAD * HH * 2);
    u16*   ybuf  = (u16*)take((size_t)MPAD * HH * 2);
    float* pmax  = (float*)take((size_t)40 * HH * 4);
    float* psum  = (float*)take((size_t)40 * HH * 4);

    k_scanwt<<<NN + WT_BLOCKS, 256, 0, stream>>>(feat, adj, W0, W1, W2, flag,
                                                 ellc, ellv, cnt, dinv, w0t, w1t, w2t);

    dim3 gg(2, MPAD / 32);  // (2, 316) -> 632 blocks
    k_mfma<<<gg, 256, 0, stream>>>(feat, w0t, flag, 1, ybuf, FDIN);
    k_agg<<<NN / 2, 256, 0, stream>>>((const u32*)ybuf, ellc, ellv, cnt, dinv, b0, flag, (u32*)xbuf);
    k_mfma<<<gg, 256, 0, stream>>>(xbuf, w1t, flag, 0, ybuf, HH);
    k_agg<<<NN / 2, 256, 0, stream>>>((const u32*)ybuf, ellc, ellv, cnt, dinv, b1, flag, (u32*)xbuf);
    k_mfma<<<gg, 256, 0, stream>>>(xbuf, w2t, flag, 0, ybuf, HH);
    k_agg<<<NN / 2, 256, 0, stream>>>((const u32*)ybuf, ellc, ellv, cnt, dinv, b2, flag, (u32*)xbuf);

    k_pool<<<40, 256, 0, stream>>>(xbuf, pmax, psum);
    k_head<<<1, 256, 0, stream>>>(pmax, psum, C1w, c1b, C2w, c2b, C3w, c3b, flag, d_out);
}

// Round 7
// 338.132 us; speedup vs baseline: 1.3491x; 1.3491x over previous
//
#include <hip/hip_runtime.h>
#include <hip/hip_bf16.h>

#define NN 10000
#define FDIN 1024
#define HH 256
#define CAP 64
#define MPAD 10112        // 158 * 64
#define WT_BLOCKS 1536    // (FDIN*HH + 2*HH*HH) / 256
#define FCONV_BLOCKS 5000 // NN*FDIN/8/256

typedef unsigned short u16;
typedef unsigned int u32;
typedef __attribute__((ext_vector_type(8))) short short8;
typedef __attribute__((ext_vector_type(4))) float f32x4;

__device__ __forceinline__ float ld_in(const void* p, size_t i, int bf) {
    if (bf) {
        unsigned short u = ((const unsigned short*)p)[i];
        return __uint_as_float(((unsigned int)u) << 16);
    }
    return ((const float*)p)[i];
}

__device__ __forceinline__ u16 bf16bits(float x) {
    __hip_bfloat16 h = __float2bfloat16(x);   // RNE
    return *(u16*)&h;
}

__device__ __forceinline__ float bf16val(u16 u) {
    return __uint_as_float(((unsigned int)u) << 16);
}

// Async global->LDS, 16B per lane. LDS dest = wave-uniform base + lane*16.
__device__ __forceinline__ void gload16(const void* g, void* l) {
    __builtin_amdgcn_global_load_lds((const __attribute__((address_space(1))) void*)g,
                                     (__attribute__((address_space(3))) void*)l, 16, 0, 0);
}

// Per-block dtype detect (512 B broadcast read, L2-hit after first block).
__device__ __forceinline__ int local_flag(const void* feat, int tid, int* cnts) {
    u16 u = ((const u16*)feat)[2 * tid];
    int e = (u >> 7) & 0xFF;
    bool pred = (e >= 100 && e <= 137);
    unsigned long long b = __ballot(pred);
    if ((tid & 63) == 0) cnts[tid >> 6] = __popcll(b);
    __syncthreads();
    return (cnts[0] + cnts[1] + cnts[2] + cnts[3]) >= 128;
}

// Fused front-end. Blocks [0,NN): adjacency row scan -> ELL + dinv.
// Blocks [NN, NN+WT_BLOCKS): weight transpose W[K][256] -> Wt[256][K] bf16.
// Blocks [NN+WT_BLOCKS, +FCONV_BLOCKS): feat fp32->bf16 convert (only if fp32).
__global__ __launch_bounds__(256) void k_scanconv(const void* __restrict__ feat,
                                                  const void* __restrict__ adj,
                                                  const void* __restrict__ W0,
                                                  const void* __restrict__ W1,
                                                  const void* __restrict__ W2,
                                                  int* __restrict__ flag,
                                                  int* __restrict__ ellc,
                                                  float* __restrict__ ellv,
                                                  int* __restrict__ cnt,
                                                  float* __restrict__ dinv,
                                                  u16* __restrict__ featb,
                                                  u16* __restrict__ w0t,
                                                  u16* __restrict__ w1t,
                                                  u16* __restrict__ w2t) {
    __shared__ int cnts[4];
    __shared__ int s_cnt;
    __shared__ float s_sum;
    int tid = threadIdx.x;
    int bid = blockIdx.x;
    if (tid == 0) { s_cnt = 0; s_sum = 0.f; }
    int f = local_flag(feat, tid, cnts);   // includes one __syncthreads
    if (bid == 0 && tid == 0) *flag = f;

    if (bid < NN) {
        int i = bid;
        float lsum = 0.f;
        if (f) {
            const uint4* p = (const uint4*)((const u16*)adj + (size_t)i * NN);
            for (int t = tid; t < NN / 8; t += 256) {
                uint4 q = p[t];
                if ((q.x | q.y | q.z | q.w) == 0u) continue;   // ~98% of groups
                unsigned int w_[4] = {q.x, q.y, q.z, q.w};
                #pragma unroll
                for (int w = 0; w < 4; ++w) {
                    #pragma unroll
                    for (int hh = 0; hh < 2; ++hh) {
                        unsigned short u = (unsigned short)(w_[w] >> (16 * hh));
                        if (u) {
                            float v = bf16val(u);
                            lsum += v;
                            int slot = atomicAdd(&s_cnt, 1);
                            if (slot < CAP) {
                                ellc[(size_t)i * CAP + slot] = t * 8 + w * 2 + hh;
                                ellv[(size_t)i * CAP + slot] = v;
                            }
                        }
                    }
                }
            }
        } else {
            const uint4* p = (const uint4*)((const float*)adj + (size_t)i * NN);
            for (int t = tid; t < NN / 4; t += 256) {
                uint4 qi = p[t];
                if ((qi.x | qi.y | qi.z | qi.w) == 0u) continue;
                unsigned int w_[4] = {qi.x, qi.y, qi.z, qi.w};
                #pragma unroll
                for (int w = 0; w < 4; ++w) {
                    float v = __uint_as_float(w_[w]);
                    if (v != 0.f) {
                        lsum += v;
                        int slot = atomicAdd(&s_cnt, 1);
                        if (slot < CAP) {
                            ellc[(size_t)i * CAP + slot] = t * 4 + w;
                            ellv[(size_t)i * CAP + slot] = v;
                        }
                    }
                }
            }
        }
        for (int off = 32; off > 0; off >>= 1) lsum += __shfl_down(lsum, off, 64);
        if ((tid & 63) == 0) atomicAdd(&s_sum, lsum);
        __syncthreads();
        if (tid == 0) {
            float deg = s_sum + 1.0f;
            dinv[i] = rsqrtf(deg);
            cnt[i] = s_cnt < CAP ? s_cnt : CAP;
        }
        return;
    }
    if (bid < NN + WT_BLOCKS) {
        int idx = (bid - NN) * 256 + tid;
        const void* W; u16* Wt; int K;
        if (idx < FDIN * HH)                { W = W0; Wt = w0t; K = FDIN; }
        else if (idx < FDIN * HH + HH * HH) { W = W1; Wt = w1t; K = HH; idx -= FDIN * HH; }
        else                                { W = W2; Wt = w2t; K = HH; idx -= FDIN * HH + HH * HH; }
        int k = idx >> 8, n = idx & 255;
        Wt[(size_t)n * K + k] = bf16bits(ld_in(W, (size_t)idx, f));
        return;
    }
    if (f) return;   // features already bf16
    int idx = (bid - NN - WT_BLOCKS) * 256 + tid;   // one per 8 elems, rows < NN
    int row = idx >> 7;
    int c0 = (idx & 127) * 8;
    const float* fp = (const float*)feat + (size_t)row * FDIN + c0;
    float4 v0 = *(const float4*)fp;
    float4 v1 = *(const float4*)(fp + 4);
    float vv[8] = {v0.x, v0.y, v0.z, v0.w, v1.x, v1.y, v1.z, v1.w};
    u16 outv[8];
    #pragma unroll
    for (int e = 0; e < 8; ++e) outv[e] = bf16bits(vv[e]);
    *(uint4*)(featb + (size_t)row * FDIN + c0) = *(const uint4*)outv;
}

// ---- MFMA GEMM: BM=64, BN=128, BK=64; 4 waves 2x2; wave tile 32x64.
// Staging via global_load_lds (16B/lane): linear LDS dest + inverse-swizzled
// per-lane global source (rule #21 / m173). LDS image = XOR-16B swizzled tile,
// read back with the same XOR. Double-buffered: A0|A1|B0|B1 = 48 KB.

__device__ __forceinline__ void compute64(const unsigned char* Asb, const unsigned char* Bsb,
                                          int l, int wm, int wn, f32x4 acc[2][4]) {
    #pragma unroll
    for (int kk = 0; kk < 2; ++kk) {
        int kb = kk * 64 + ((l >> 4) << 4);
        short8 av[2], bv[4];
        #pragma unroll
        for (int i = 0; i < 2; ++i) {
            int row = wm * 32 + i * 16 + (l & 15);
            av[i] = *(const short8*)(Asb + row * 128 + (kb ^ ((row & 7) << 4)));
        }
        #pragma unroll
        for (int j = 0; j < 4; ++j) {
            int n = wn * 64 + j * 16 + (l & 15);
            bv[j] = *(const short8*)(Bsb + n * 128 + (kb ^ ((n & 7) << 4)));
        }
        #pragma unroll
        for (int i = 0; i < 2; ++i)
            #pragma unroll
            for (int j = 0; j < 4; ++j)
                acc[i][j] = __builtin_amdgcn_mfma_f32_16x16x32_bf16(av[i], bv[j], acc[i][j], 0, 0, 0);
    }
}

// A = (*flag) ? A1 : A2. A rows clamp to NN-1 (pad outputs unused downstream).
__global__ __launch_bounds__(256) void k_mfma(const u16* __restrict__ A1,
                                              const u16* __restrict__ A2,
                                              const u16* __restrict__ Bt,
                                              const int* __restrict__ flag,
                                              u16* __restrict__ Y, int K) {
    __shared__ uint4 lds4[3072];   // 48 KB: A0 8K | A1 8K | B0 16K | B1 16K
    unsigned char* Abase = (unsigned char*)lds4;
    unsigned char* Bbase = Abase + 16384;
    const u16* A = (*flag) ? A1 : A2;
    const int tid = threadIdx.x;
    const int l = tid & 63;
    const int wid = tid >> 6;
    const int wm = wid >> 1, wn = wid & 1;
    const int m0 = blockIdx.y * 64;
    const int n0 = blockIdx.x * 128;
    const int bofs = ((l & 7) ^ (l >> 3)) << 4;   // swizzled byte-in-row source
    const int rsub = l >> 3;
    const size_t Kb = (size_t)K * 2;

    f32x4 acc[2][4] = {};
    auto stage = [&](int k0, int buf) {
        unsigned char* Ab = Abase + (buf << 13);
        unsigned char* Bb = Bbase + (buf << 14);
        int kB = k0 << 1;
        #pragma unroll
        for (int q = 0; q < 2; ++q) {
            int i = wid + (q << 2);            // A issue 0..7, rows i*8..i*8+7
            int row = m0 + (i << 3) + rsub;
            if (row > NN - 1) row = NN - 1;
            gload16((const unsigned char*)A + (size_t)row * Kb + kB + bofs,
                    Ab + (i << 10));
        }
        #pragma unroll
        for (int q = 0; q < 4; ++q) {
            int i = wid + (q << 2);            // B issue 0..15
            int n = n0 + (i << 3) + rsub;
            gload16((const unsigned char*)Bt + (size_t)n * Kb + kB + bofs,
                    Bb + (i << 10));
        }
    };

    stage(0, 0);
    const int nt = K >> 6;
    __syncthreads();                            // drains prologue loads
    for (int t = 0; t < nt; ++t) {
        if (t + 1 < nt) stage((t + 1) << 6, (t + 1) & 1);
        compute64(Abase + ((t & 1) << 13), Bbase + ((t & 1) << 14), l, wm, wn, acc);
        __syncthreads();                        // all reads done + next loads drained
    }
    #pragma unroll
    for (int i = 0; i < 2; ++i) {
        int r0 = m0 + wm * 32 + i * 16 + ((l >> 4) << 2);
        #pragma unroll
        for (int j = 0; j < 4; ++j) {
            int col = n0 + wn * 64 + j * 16 + (l & 15);
            #pragma unroll
            for (int r = 0; r < 4; ++r)
                Y[(size_t)(r0 + r) * HH + col] = bf16bits(acc[i][j][r]);
        }
    }
}

// x_out[i,:] = bf16(relu(dinv_i*(sum_e w*dinv_c*y[c,:] + dinv_i*y[i,:]) + bias))
__global__ __launch_bounds__(128) void k_agg(const u32* __restrict__ y,
                                             const int* __restrict__ ellc,
                                             const float* __restrict__ ellv,
                                             const int* __restrict__ cnt,
                                             const float* __restrict__ dinv,
                                             const void* __restrict__ bias,
                                             const int* __restrict__ flag,
                                             u32* __restrict__ xout) {
    int i = blockIdx.x, j = threadIdx.x;
    int f = *flag;
    float di = dinv[i];
    u32 w = y[(size_t)i * 128 + j];
    float a0 = di * bf16val((u16)(w & 0xffff));
    float a1 = di * bf16val((u16)(w >> 16));
    int c_ = cnt[i];
    for (int e = 0; e < c_; ++e) {
        int c = ellc[(size_t)i * CAP + e];
        float s = ellv[(size_t)i * CAP + e] * dinv[c];
        u32 v = y[(size_t)c * 128 + j];
        a0 = fmaf(s, bf16val((u16)(v & 0xffff)), a0);
        a1 = fmaf(s, bf16val((u16)(v >> 16)), a1);
    }
    float v0 = fmaf(di, a0, ld_in(bias, (size_t)(2 * j), f));
    float v1 = fmaf(di, a1, ld_in(bias, (size_t)(2 * j + 1), f));
    v0 = v0 > 0.f ? v0 : 0.f;
    v1 = v1 > 0.f ? v1 : 0.f;
    xout[(size_t)i * 128 + j] = (u32)bf16bits(v0) | ((u32)bf16bits(v1) << 16);
}

// 40 blocks x 250 rows; per-block partial max/sum, no atomics.
__global__ __launch_bounds__(256) void k_pool(const u16* __restrict__ x,
                                              float* __restrict__ pmax,
                                              float* __restrict__ psum) {
    int j = threadIdx.x, b = blockIdx.x;
    int r0 = b * 250;
    float m = 0.f, s = 0.f;
    for (int r = r0; r < r0 + 250; ++r) {
        float v = bf16val(x[(size_t)r * HH + j]);
        m = fmaxf(m, v);
        s += v;
    }
    pmax[b * HH + j] = m;
    psum[b * HH + j] = s;
}

__global__ __launch_bounds__(256) void k_head(const float* __restrict__ pmax,
                                              const float* __restrict__ psum,
                                              const void* C1w, const void* c1b,
                                              const void* C2w, const void* c2b,
                                              const void* C3w, const void* c3b,
                                              const int* __restrict__ flag,
                                              void* __restrict__ out) {
    __shared__ float gs[2 * HH], h1[HH], h2[HH / 2];
    int j = threadIdx.x;
    int f = *flag;
    float m = 0.f, s = 0.f;
    #pragma unroll 4
    for (int b = 0; b < 40; ++b) {
        m = fmaxf(m, pmax[b * HH + j]);
        s += psum[b * HH + j];
    }
    gs[j] = m;
    gs[HH + j] = s * (1.0f / (float)NN);
    __syncthreads();
    float a = 0.f;
    for (int k = 0; k < 2 * HH; ++k) a = fmaf(gs[k], ld_in(C1w, (size_t)k * HH + j, f), a);
    a += ld_in(c1b, j, f);
    h1[j] = a > 0.f ? a : 0.f;
    __syncthreads();
    if (j < HH / 2) {
        float b2_ = 0.f;
        for (int k = 0; k < HH; ++k) b2_ = fmaf(h1[k], ld_in(C2w, (size_t)k * (HH / 2) + j, f), b2_);
        b2_ += ld_in(c2b, j, f);
        h2[j] = b2_ > 0.f ? b2_ : 0.f;
    }
    __syncthreads();
    if (j < 3) {
        float o = 0.f;
        for (int k = 0; k < HH / 2; ++k) o = fmaf(h2[k], ld_in(C3w, (size_t)k * 3 + j, f), o);
        o += ld_in(c3b, j, f);
        if (f) ((__hip_bfloat16*)out)[j] = __float2bfloat16(o);
        else   ((float*)out)[j] = o;
    }
}

extern "C" void kernel_launch(void* const* d_in, const int* in_sizes, int n_in,
                              void* d_out, int out_size, void* d_ws, size_t ws_size,
                              hipStream_t stream) {
    const void* feat = d_in[0];
    const void* adj  = d_in[1];
    const void* W0 = d_in[2];  const void* b0 = d_in[3];
    const void* W1 = d_in[4];  const void* b1 = d_in[5];
    const void* W2 = d_in[6];  const void* b2 = d_in[7];
    const void* C1w = d_in[8]; const void* c1b = d_in[9];
    const void* C2w = d_in[10]; const void* c2b = d_in[11];
    const void* C3w = d_in[12]; const void* c3b = d_in[13];

    char* ws = (char*)d_ws;
    size_t o = 0;
    auto take = [&](size_t bytes) -> void* {
        void* p = ws + o;
        o += (bytes + 255) & ~(size_t)255;
        return p;
    };
    int*   flag  = (int*)take(4);
    float* dinv  = (float*)take((size_t)NN * 4);
    int*   cnt   = (int*)take((size_t)NN * 4);
    int*   ellc  = (int*)take((size_t)NN * CAP * 4);
    float* ellv  = (float*)take((size_t)NN * CAP * 4);
    u16*   featb = (u16*)take((size_t)NN * FDIN * 2);
    u16*   w0t   = (u16*)take((size_t)HH * FDIN * 2);
    u16*   w1t   = (u16*)take((size_t)HH * HH * 2);
    u16*   w2t   = (u16*)take((size_t)HH * HH * 2);
    u16*   xbuf  = (u16*)take((size_t)MPAD * HH * 2);
    u16*   ybuf  = (u16*)take((size_t)MPAD * HH * 2);
    float* pmax  = (float*)take((size_t)40 * HH * 4);
    float* psum  = (float*)take((size_t)40 * HH * 4);

    k_scanconv<<<NN + WT_BLOCKS + FCONV_BLOCKS, 256, 0, stream>>>(
        feat, adj, W0, W1, W2, flag, ellc, ellv, cnt, dinv, featb, w0t, w1t, w2t);

    dim3 gg(2, MPAD / 64);  // (2, 158)
    k_mfma<<<gg, 256, 0, stream>>>((const u16*)feat, featb, w0t, flag, ybuf, FDIN);
    k_agg<<<NN, 128, 0, stream>>>((const u32*)ybuf, ellc, ellv, cnt, dinv, b0, flag, (u32*)xbuf);
    k_mfma<<<gg, 256, 0, stream>>>(xbuf, xbuf, w1t, flag, ybuf, HH);
    k_agg<<<NN, 128, 0, stream>>>((const u32*)ybuf, ellc, ellv, cnt, dinv, b1, flag, (u32*)xbuf);
    k_mfma<<<gg, 256, 0, stream>>>(xbuf, xbuf, w2t, flag, ybuf, HH);
    k_agg<<<NN, 128, 0, stream>>>((const u32*)ybuf, ellc, ellv, cnt, dinv, b2, flag, (u32*)xbuf);

    k_pool<<<40, 256, 0, stream>>>(xbuf, pmax, psum);
    k_head<<<1, 256, 0, stream>>>(pmax, psum, C1w, c1b, C2w, c2b, C3w, c3b, flag, d_out);
}